// Round 1
// baseline (529.560 us; speedup 1.0000x reference)
//
#include <hip/hip_runtime.h>
#include <hip/hip_bf16.h>

// Problem geometry (fixed by the reference):
//   bilateral_grid: (N=8, C=12, GD=8, GH=16, GW=16) f32
//   guidemap:       (N=8, 1, H=1024, W=1024) f32
//   output:         (N=8, C=12, H=1024, W=1024) f32
// Reference uses grid[n, y, x, z, c] = bilateral_grid[n, c, z, y, x].

#define N_ 8
#define C_ 12
#define GD 8
#define GH 16
#define GW 16
#define H_ 1024
#define W_ 1024

// ---------------------------------------------------------------------------
// Kernel 1: transpose bilateral_grid [n][c][z][y][x] -> t [n][y][x][z][c]
// 196608 elements total (786 KB) — negligible cost, sets up float4-able loads.
// ---------------------------------------------------------------------------
__global__ void transpose_grid_kernel(const float* __restrict__ in,
                                      float* __restrict__ out) {
    int idx = blockIdx.x * 256 + threadIdx.x;   // 0 .. 196607
    // decode as OUTPUT index: (((n*GH + y)*GW + x)*GD + z)*C_ + c
    int c = idx % C_;
    int r = idx / C_;
    int z = r & (GD - 1); r >>= 3;
    int x = r & (GW - 1); r >>= 4;
    int y = r & (GH - 1);
    int n = r >> 4;
    // input offset: (((n*C_ + c)*GD + z)*GH + y)*GW + x
    size_t src = ((((size_t)n * C_ + c) * GD + z) * GH + y) * GW + x;
    out[idx] = in[src];
}

// ---------------------------------------------------------------------------
// Kernel 2: slice. One thread per pixel, all 12 channels.
// USE_T: read from transposed grid (float4 path) vs raw grid (scalar path).
// ---------------------------------------------------------------------------
template <bool USE_T>
__global__ __launch_bounds__(256) void slice_kernel(
        const float* __restrict__ grid_raw,   // [n][c][z][y][x]
        const float* __restrict__ grid_t,     // [n][y][x][z][c]
        const float* __restrict__ guide,      // [n][y][x]
        float* __restrict__ out)              // [n][c][y][x]
{
    const int x = blockIdx.x * 256 + threadIdx.x;
    const int y = blockIdx.y;
    const int n = blockIdx.z;

    const float gv = guide[((size_t)n * H_ + y) * W_ + x];

    // gw/w == gh/h == 16/1024 == 1/64 exactly
    const float gx = ((float)x + 0.5f) * (1.0f / 64.0f);
    const float gy = ((float)y + 0.5f) * (1.0f / 64.0f);
    const float gz = gv * (float)GD;

    const float fx = floorf(gx - 0.5f);
    const float fy = floorf(gy - 0.5f);
    const float fz = floorf(gz - 0.5f);

    const float wx1 = gx - 0.5f - fx;
    const float wy1 = gy - 0.5f - fy;
    const float wz1 = gz - 0.5f - fz;

    const int x0 = (int)fminf(fmaxf(fx,        0.0f), (float)(GW - 1));
    const int x1 = (int)fminf(fmaxf(fx + 1.0f, 0.0f), (float)(GW - 1));
    const int y0 = (int)fminf(fmaxf(fy,        0.0f), (float)(GH - 1));
    const int y1 = (int)fminf(fmaxf(fy + 1.0f, 0.0f), (float)(GH - 1));
    const int z0 = (int)fminf(fmaxf(fz,        0.0f), (float)(GD - 1));
    const int z1 = (int)fminf(fmaxf(fz + 1.0f, 0.0f), (float)(GD - 1));

    const int   zs[2]  = { z0, z1 };
    const float wzs[2] = { 1.0f - wz1, wz1 };
    const int   ys[2]  = { y0, y1 };
    const float wys[2] = { 1.0f - wy1, wy1 };
    const int   xs[2]  = { x0, x1 };
    const float wxs[2] = { 1.0f - wx1, wx1 };

    float acc[C_];
#pragma unroll
    for (int c = 0; c < C_; ++c) acc[c] = 0.0f;

    // reference summation order: z outer, then y, then x
#pragma unroll
    for (int zz = 0; zz < 2; ++zz) {
#pragma unroll
        for (int yy = 0; yy < 2; ++yy) {
#pragma unroll
            for (int xx = 0; xx < 2; ++xx) {
                const float wgt = wys[yy] * wxs[xx] * wzs[zz];
                if (USE_T) {
                    const float4* p = (const float4*)grid_t +
                        ((((size_t)n * GH + ys[yy]) * GW + xs[xx]) * GD + zs[zz]) * 3;
                    const float4 a = p[0];
                    const float4 b = p[1];
                    const float4 d = p[2];
                    acc[0]  += wgt * a.x;  acc[1]  += wgt * a.y;
                    acc[2]  += wgt * a.z;  acc[3]  += wgt * a.w;
                    acc[4]  += wgt * b.x;  acc[5]  += wgt * b.y;
                    acc[6]  += wgt * b.z;  acc[7]  += wgt * b.w;
                    acc[8]  += wgt * d.x;  acc[9]  += wgt * d.y;
                    acc[10] += wgt * d.z;  acc[11] += wgt * d.w;
                } else {
                    const float* p = grid_raw +
                        (((size_t)n * C_) * GD + zs[zz]) * (GH * GW) +
                        ys[yy] * GW + xs[xx];
#pragma unroll
                    for (int c = 0; c < C_; ++c)
                        acc[c] += wgt * p[(size_t)c * (GD * GH * GW)];
                }
            }
        }
    }

    const size_t ob = ((size_t)n * C_) * (size_t)(H_ * W_) + (size_t)y * W_ + x;
#pragma unroll
    for (int c = 0; c < C_; ++c)
        out[ob + (size_t)c * (H_ * W_)] = acc[c];
}

extern "C" void kernel_launch(void* const* d_in, const int* in_sizes, int n_in,
                              void* d_out, int out_size, void* d_ws, size_t ws_size,
                              hipStream_t stream) {
    const float* grid_raw = (const float*)d_in[0];  // (8,12,8,16,16)
    const float* guide    = (const float*)d_in[1];  // (8,1,1024,1024)
    float* out = (float*)d_out;

    const size_t t_bytes = (size_t)N_ * GH * GW * GD * C_ * sizeof(float); // 786432

    const dim3 sgrid(W_ / 256, H_, N_);
    const dim3 sblock(256);

    if (ws_size >= t_bytes) {
        float* grid_t = (float*)d_ws;
        transpose_grid_kernel<<<dim3((N_ * GH * GW * GD * C_) / 256), dim3(256),
                                0, stream>>>(grid_raw, grid_t);
        slice_kernel<true><<<sgrid, sblock, 0, stream>>>(grid_raw, grid_t, guide, out);
    } else {
        slice_kernel<false><<<sgrid, sblock, 0, stream>>>(grid_raw, nullptr, guide, out);
    }
}

// Round 3
// 459.837 us; speedup vs baseline: 1.1516x; 1.1516x over previous
//
#include <hip/hip_runtime.h>
#include <hip/hip_bf16.h>

// Geometry (fixed by the reference):
//   bilateral_grid: (N=8, C=12, GD=8, GH=16, GW=16) f32   [n][c][z][y][x]
//   guidemap:       (N=8, 1, H=1024, W=1024) f32
//   output:         (N=8, C=12, H=1024, W=1024) f32
// Reference grid[n,y,x,z,c] = bilateral_grid[n,c,z,y,x]; gh/h = gw/w = 1/64.

#define N_ 8
#define C_ 12
#define GD 8
#define GH 16
#define GW 16
#define H_ 1024
#define W_ 1024

typedef float v4f __attribute__((ext_vector_type(4)));

// Block = 256 threads, one full output row (n, y), 4 px/thread.
// LDS slab: the two grid rows (y0,y1) this row needs, transposed to
// [yy][x][z][c] so each (corner, z) is 3 contiguous float4s.
__global__ __launch_bounds__(256) void slice_row_kernel(
        const float* __restrict__ grid_raw,   // [n][c][z][y][x]
        const float* __restrict__ guide,      // [n][y][x]
        float* __restrict__ out)              // [n][c][y][x]
{
    __shared__ float slab[2 * GW * GD * C_];  // [yy][x][z][c] = 3072 f = 12 KB

    const int tid = threadIdx.x;
    const int y   = blockIdx.y;
    const int n   = blockIdx.z;

    // ---- per-row y interpolation setup (uniform across block) ----
    const float gy  = ((float)y + 0.5f) * (1.0f / 64.0f);
    const float fy  = floorf(gy - 0.5f);
    const float wy1 = gy - 0.5f - fy;
    const int y0 = (int)fminf(fmaxf(fy,        0.0f), (float)(GH - 1));
    const int y1 = (int)fminf(fmaxf(fy + 1.0f, 0.0f), (float)(GH - 1));

    // ---- cooperative slab load: 3072 elements, 12 per thread ----
    // eid = k*256+tid; decode so consecutive tid -> consecutive x (coalesced 64B runs)
#pragma unroll
    for (int k = 0; k < 12; ++k) {
        int eid = k * 256 + tid;
        int x   = eid & (GW - 1);
        int r   = eid >> 4;
        int yy  = r & 1;  r >>= 1;
        int z   = r & (GD - 1);
        int c   = r >> 3;
        int ysel = yy ? y1 : y0;
        // src: (((n*C + c)*GD + z)*GH + ysel)*GW + x
        slab[((yy * GW + x) * GD + z) * C_ + c] =
            grid_raw[(((size_t)n * C_ + c) * GD + z) * (GH * GW) + ysel * GW + x];
    }
    __syncthreads();

    const float wys[2] = { 1.0f - wy1, wy1 };

    // ---- guide: 4 consecutive pixels per thread, vector load ----
    const v4f g4 = ((const v4f*)(guide + ((size_t)n * H_ + y) * W_))[tid];

    float vout[C_][4];

#pragma unroll
    for (int j = 0; j < 4; ++j) {
        const int px = tid * 4 + j;

        const float gx  = ((float)px + 0.5f) * (1.0f / 64.0f);
        const float fx  = floorf(gx - 0.5f);
        const float wx1 = gx - 0.5f - fx;
        const int x0 = (int)fminf(fmaxf(fx,        0.0f), (float)(GW - 1));
        const int x1 = (int)fminf(fmaxf(fx + 1.0f, 0.0f), (float)(GW - 1));

        const float gz  = g4[j] * (float)GD;
        const float fz  = floorf(gz - 0.5f);
        const float wz1 = gz - 0.5f - fz;
        const int z0 = (int)fminf(fmaxf(fz,        0.0f), (float)(GD - 1));
        const int z1 = (int)fminf(fmaxf(fz + 1.0f, 0.0f), (float)(GD - 1));

        const int   zs[2]  = { z0, z1 };
        const float wzs[2] = { 1.0f - wz1, wz1 };
        const int   xs[2]  = { x0, x1 };
        const float wxs[2] = { 1.0f - wx1, wx1 };

        float acc[C_];
#pragma unroll
        for (int c = 0; c < C_; ++c) acc[c] = 0.0f;

        // reference order: z outer, then y, then x
#pragma unroll
        for (int zz = 0; zz < 2; ++zz) {
#pragma unroll
            for (int yy = 0; yy < 2; ++yy) {
#pragma unroll
                for (int xx = 0; xx < 2; ++xx) {
                    const float wgt = wys[yy] * wxs[xx] * wzs[zz];
                    const v4f* s4 = (const v4f*)
                        &slab[((yy * GW + xs[xx]) * GD + zs[zz]) * C_];
                    const v4f a = s4[0];
                    const v4f b = s4[1];
                    const v4f d = s4[2];
                    acc[0]  += wgt * a.x;  acc[1]  += wgt * a.y;
                    acc[2]  += wgt * a.z;  acc[3]  += wgt * a.w;
                    acc[4]  += wgt * b.x;  acc[5]  += wgt * b.y;
                    acc[6]  += wgt * b.z;  acc[7]  += wgt * b.w;
                    acc[8]  += wgt * d.x;  acc[9]  += wgt * d.y;
                    acc[10] += wgt * d.z;  acc[11] += wgt * d.w;
                }
            }
        }

#pragma unroll
        for (int c = 0; c < C_; ++c) vout[c][j] = acc[c];
    }

    // ---- stores: 16B per channel, nontemporal (streaming output) ----
    const size_t ob = ((size_t)n * C_) * (size_t)(H_ * W_) + (size_t)y * W_ + (size_t)tid * 4;
#pragma unroll
    for (int c = 0; c < C_; ++c) {
        v4f v = { vout[c][0], vout[c][1], vout[c][2], vout[c][3] };
        __builtin_nontemporal_store(v, (v4f*)(out + ob + (size_t)c * (H_ * W_)));
    }
}

extern "C" void kernel_launch(void* const* d_in, const int* in_sizes, int n_in,
                              void* d_out, int out_size, void* d_ws, size_t ws_size,
                              hipStream_t stream) {
    const float* grid_raw = (const float*)d_in[0];  // (8,12,8,16,16)
    const float* guide    = (const float*)d_in[1];  // (8,1,1024,1024)
    float* out = (float*)d_out;

    const dim3 grid(1, H_, N_);   // one block per output row
    const dim3 block(256);
    slice_row_kernel<<<grid, block, 0, stream>>>(grid_raw, guide, out);
}